// Round 5
// baseline (430.220 us; speedup 1.0000x reference)
//
#include <hip/hip_runtime.h>
#include <hip/hip_bf16.h>

typedef short bf16x8 __attribute__((ext_vector_type(8)));
typedef float f32x4 __attribute__((ext_vector_type(4)));

#define AS1 __attribute__((address_space(1)))
#define AS3 __attribute__((address_space(3)))

constexpr int CB = 512;    // channels
constexpr int NB = 2048;   // sequence length
constexpr int BB = 8;      // batch

__device__ inline float b2f(short s) {
  unsigned u = ((unsigned)(unsigned short)s) << 16;
  float f; __builtin_memcpy(&f, &u, 4); return f;
}

// ---------------- wv -> bf16
__global__ void convert_wv(const float* __restrict__ wv, __hip_bfloat16* __restrict__ wvb) {
  int i = blockIdx.x * 256 + threadIdx.x;
  if (i < CB * CB) wvb[i] = __float2bfloat16(wv[i]);
}

// ---------------- G[c][d] = sum_o wq[o][c]*wk[o][d], fp32 accum, split hi/lo bf16 out
__global__ __launch_bounds__(256) void compute_G(const float* __restrict__ wq,
                                                 const float* __restrict__ wk,
                                                 __hip_bfloat16* __restrict__ Gh,
                                                 __hip_bfloat16* __restrict__ Gl) {
  __shared__ float aq[32][65];
  __shared__ float ak[32][65];
  int c0 = blockIdx.y * 64, d0 = blockIdx.x * 64;
  int t = threadIdx.x;
  int tc = t & 15, td = t >> 4;
  float acc[4][4] = {};
  for (int o0 = 0; o0 < CB; o0 += 32) {
    __syncthreads();
    int r = t >> 3, cc = (t & 7) * 8;
#pragma unroll
    for (int i = 0; i < 8; i++) {
      aq[r][cc + i] = wq[(size_t)(o0 + r) * CB + c0 + cc + i];
      ak[r][cc + i] = wk[(size_t)(o0 + r) * CB + d0 + cc + i];
    }
    __syncthreads();
#pragma unroll 8
    for (int o = 0; o < 32; o++)
#pragma unroll
      for (int i = 0; i < 4; i++)
#pragma unroll
        for (int j = 0; j < 4; j++)
          acc[i][j] += aq[o][tc * 4 + i] * ak[o][td * 4 + j];
  }
#pragma unroll
  for (int i = 0; i < 4; i++)
#pragma unroll
    for (int j = 0; j < 4; j++) {
      int c = c0 + tc * 4 + i, d = d0 + td * 4 + j;
      float v = acc[i][j];
      __hip_bfloat16 h = __float2bfloat16(v);
      Gh[(size_t)c * CB + d] = h;
      Gl[(size_t)c * CB + d] = __float2bfloat16(v - __bfloat162float(h));
    }
}

// ---------------- u[d] = sum_o bq[o]*wk[o][d]
__global__ void compute_u(const float* __restrict__ wk, const float* __restrict__ bq,
                          float* __restrict__ u) {
  int d = blockIdx.x * 256 + threadIdx.x;
  if (d >= CB) return;
  float s = 0.0f;
  for (int o = 0; o < CB; o++) s += bq[o] * wk[(size_t)o * CB + d];
  u[d] = s;
}

// ---------------- ubias[row] = sum_c u[c] * x[row][c]  (x = xbT hi+lo), row in [0, B*N)
__global__ __launch_bounds__(256) void compute_ubias(const __hip_bfloat16* __restrict__ xh,
                                                     const __hip_bfloat16* __restrict__ xl,
                                                     const float* __restrict__ u,
                                                     float* __restrict__ ub) {
  __shared__ float us[CB];
  for (int i = threadIdx.x; i < CB; i += 256) us[i] = u[i];
  __syncthreads();
  int row = blockIdx.x * 4 + (threadIdx.x >> 6);
  int lane = threadIdx.x & 63;
  bf16x8 vh = *(const bf16x8*)(xh + (size_t)row * CB + lane * 8);
  bf16x8 vl = *(const bf16x8*)(xl + (size_t)row * CB + lane * 8);
  float s = 0.0f;
#pragma unroll
  for (int i = 0; i < 8; i++) s += us[lane * 8 + i] * (b2f(vh[i]) + b2f(vl[i]));
#pragma unroll
  for (int off = 32; off; off >>= 1) s += __shfl_xor(s, off);
  if (lane == 0) ub[row] = s;
}

// ---------------- x [B][C][N] fp32 -> xbT hi/lo [B][N][C] bf16 (tiled transpose + split)
__global__ void transpose_x(const float* __restrict__ x,
                            __hip_bfloat16* __restrict__ oh, __hip_bfloat16* __restrict__ ol) {
  __shared__ float tile[32][33];
  int b = blockIdx.z, c0 = blockIdx.y * 32, n0 = blockIdx.x * 32;
  int tx = threadIdx.x, ty = threadIdx.y;          // block (32, 8)
  const float* xb = x + (size_t)b * CB * NB;
#pragma unroll
  for (int r = 0; r < 4; r++)
    tile[ty + 8 * r][tx] = xb[(size_t)(c0 + ty + 8 * r) * NB + n0 + tx];
  __syncthreads();
  size_t base = (size_t)b * NB * CB;
#pragma unroll
  for (int r = 0; r < 4; r++) {
    float v = tile[tx][ty + 8 * r];
    __hip_bfloat16 h = __float2bfloat16(v);
    size_t idx = base + (size_t)(n0 + ty + 8 * r) * CB + c0 + tx;
    oh[idx] = h;
    ol[idx] = __float2bfloat16(v - __bfloat162float(h));
  }
}

// ================= S-GEMM (proven 128^2 2-barrier split) + partial row-max epilogue ===========
// S[z][i][j] = sum_c xbT[i][c]*YT[j][c] + ub[z][j]; also pmax[z][i][cb] = max over this
// wave's 64 cols (cb = blockIdx.x*2 + wc).
__global__ __launch_bounds__(256) void gemm_s128(
    const __hip_bfloat16* __restrict__ Ah, const __hip_bfloat16* __restrict__ Al,
    const __hip_bfloat16* __restrict__ Bh, const __hip_bfloat16* __restrict__ Bl,
    float* __restrict__ So, const float* __restrict__ ub, float* __restrict__ pmax) {
  constexpr int TSZ = 128 * 32;
  __shared__ alignas(16) __hip_bfloat16 sm[2 * 4 * TSZ];   // 2 bufs x 4 planes x 8KB

  const int t = threadIdx.x, z = blockIdx.z;
  const size_t zo = (size_t)z * NB * CB;
  const __hip_bfloat16* Abh = Ah + zo + (size_t)(blockIdx.y * 128) * CB;
  const __hip_bfloat16* Abl = Al + zo + (size_t)(blockIdx.y * 128) * CB;
  const __hip_bfloat16* Bbh = Bh + zo + (size_t)(blockIdx.x * 128) * CB;
  const __hip_bfloat16* Bbl = Bl + zo + (size_t)(blockIdx.x * 128) * CB;
  const int wid = t >> 6, l15 = t & 15, hi = (t >> 4) & 3;
  const int wr = wid >> 1, wc = wid & 1;
  const int lineA = t >> 2, eoff = (t & 3) * 8;

  f32x4 acc[4][4] = {};

  auto stage = [&](int buf, int kt) {
    __hip_bfloat16* base = sm + buf * (4 * TSZ);
#pragma unroll
    for (int p = 0; p < 2; p++) {
      size_t go = (size_t)(p * 64 + lineA) * CB + kt * 32 + eoff;
      int lo = p * 2048 + t * 8;
      __builtin_amdgcn_global_load_lds((const AS1 void*)(Abh + go), (AS3 void*)(base + lo), 16, 0, 0);
      __builtin_amdgcn_global_load_lds((const AS1 void*)(Bbh + go), (AS3 void*)(base + TSZ + lo), 16, 0, 0);
      __builtin_amdgcn_global_load_lds((const AS1 void*)(Abl + go), (AS3 void*)(base + 2 * TSZ + lo), 16, 0, 0);
      __builtin_amdgcn_global_load_lds((const AS1 void*)(Bbl + go), (AS3 void*)(base + 3 * TSZ + lo), 16, 0, 0);
    }
  };

  stage(0, 0);
  __syncthreads();
  int cur = 0;
  for (int kt = 0; kt < 16; kt++) {
    if (kt + 1 < 16) stage(cur ^ 1, kt + 1);
    const __hip_bfloat16* bb = sm + cur * (4 * TSZ);
    bf16x8 afh[4], bfh[4], afl[4], bfl[4];
#pragma unroll
    for (int f = 0; f < 4; f++) {
      int ao = (wr * 64 + f * 16 + l15) * 32 + hi * 8;
      int bo = (wc * 64 + f * 16 + l15) * 32 + hi * 8;
      afh[f] = *(const bf16x8*)(bb + ao);
      bfh[f] = *(const bf16x8*)(bb + TSZ + bo);
      afl[f] = *(const bf16x8*)(bb + 2 * TSZ + ao);
      bfl[f] = *(const bf16x8*)(bb + 3 * TSZ + bo);
    }
#pragma unroll
    for (int pass = 0; pass < 3; pass++) {
#pragma unroll
      for (int fm = 0; fm < 4; fm++)
#pragma unroll
        for (int fn = 0; fn < 4; fn++) {
          const bf16x8 a = (pass == 2) ? afl[fm] : afh[fm];
          const bf16x8 b = (pass == 1) ? bfl[fn] : bfh[fn];
          acc[fm][fn] = __builtin_amdgcn_mfma_f32_16x16x32_bf16(a, b, acc[fm][fn], 0, 0, 0);
        }
    }
    __syncthreads();
    cur ^= 1;
  }

  const int row0 = blockIdx.y * 128 + wr * 64;
  const int col0 = blockIdx.x * 128 + wc * 64;
  float* Sz = So + (size_t)z * NB * NB;
  const float* ubz = ub + (size_t)z * NB;
  float* pmz = pmax + (size_t)z * NB * 32;
  const int cb = blockIdx.x * 2 + wc;
#pragma unroll
  for (int fm = 0; fm < 4; fm++) {
#pragma unroll
    for (int r = 0; r < 4; r++) {
      int row = row0 + fm * 16 + hi * 4 + r;
      float mx = -3.4e38f;
#pragma unroll
      for (int fn = 0; fn < 4; fn++) {
        int col = col0 + fn * 16 + l15;
        float val = acc[fm][fn][r] + ubz[col];
        Sz[(size_t)row * NB + col] = val;
        mx = fmaxf(mx, val);
      }
      mx = fmaxf(mx, __shfl_xor(mx, 1));
      mx = fmaxf(mx, __shfl_xor(mx, 2));
      mx = fmaxf(mx, __shfl_xor(mx, 4));
      mx = fmaxf(mx, __shfl_xor(mx, 8));
      if (l15 == 0) pmz[(size_t)row * 32 + cb] = mx;
    }
  }
}

// ---------------- rowm[i] = max over 32 partials, i in [0, 4*NB)
__global__ void reduce_rowmax(const float* __restrict__ pmax, float* __restrict__ rowm) {
  int i = blockIdx.x * 256 + threadIdx.x;
  if (i >= 4 * NB) return;
  const float* p = pmax + (size_t)i * 32;
  float m = p[0];
#pragma unroll
  for (int c = 1; c < 32; c++) m = fmaxf(m, p[c]);
  rowm[i] = m;
}

// ================= PV GEMM with fused softmax ===================================
// O[z][c][i] = (sum_j V[z][c][j] * exp(S[z][i][j]-m_i)) / l_i + X[z][c][i]
// A = V (bf16, gload_lds dbuf), B = exp(S-m) (reg-staged fp32->exp->bf16->LDS),
// l_i accumulated from staged bf16 values, epilogue normalizes.
struct alignas(16) H8 { __hip_bfloat16 h[8]; };

__global__ __launch_bounds__(256) void gemm_pv(
    const __hip_bfloat16* __restrict__ V, const float* __restrict__ Sf,
    const float* __restrict__ rowm, const float* __restrict__ X, float* __restrict__ O) {
  constexpr int TSZ = 128 * 32;
  __shared__ alignas(16) __hip_bfloat16 As[2 * TSZ];
  __shared__ alignas(16) __hip_bfloat16 Bs[2 * TSZ];
  __shared__ float lred[128][2];

  const int t = threadIdx.x, z = blockIdx.z;
  const __hip_bfloat16* Ab = V + (size_t)z * CB * NB + (size_t)(blockIdx.y * 128) * NB;
  const float* Sb = Sf + (size_t)z * NB * NB + (size_t)(blockIdx.x * 128) * NB;
  const int wid = t >> 6, l15 = t & 15, hi = (t >> 4) & 3;
  const int wr = wid >> 1, wc = wid & 1;
  const int lineA = t >> 2, eoff = (t & 3) * 8;
  const int brow = t >> 1, bj = (t & 1) * 16;          // B staging: 1 row, 16 fp32 per thread
  const float mrow = rowm[(size_t)z * NB + blockIdx.x * 128 + brow];
  float lsum = 0.0f;
  float br[16];
  f32x4 acc[4][4] = {};

  auto stageA = [&](int buf, int kt) {
#pragma unroll
    for (int p = 0; p < 2; p++)
      __builtin_amdgcn_global_load_lds(
          (const AS1 void*)(Ab + (size_t)(p * 64 + lineA) * NB + kt * 32 + eoff),
          (AS3 void*)(As + buf * TSZ + p * 2048 + t * 8), 16, 0, 0);
  };
  auto loadB = [&](int kt) {
    const float4* src = (const float4*)(Sb + (size_t)brow * NB + kt * 32 + bj);
#pragma unroll
    for (int q = 0; q < 4; q++) {
      float4 v4 = src[q];
      br[q * 4 + 0] = v4.x; br[q * 4 + 1] = v4.y; br[q * 4 + 2] = v4.z; br[q * 4 + 3] = v4.w;
    }
  };
  auto packB = [&](int buf) {
    H8 o0, o1; float s = 0.0f;
#pragma unroll
    for (int i = 0; i < 8; i++) {
      __hip_bfloat16 hh = __float2bfloat16(__expf(br[i] - mrow));
      s += __bfloat162float(hh); o0.h[i] = hh;
    }
#pragma unroll
    for (int i = 0; i < 8; i++) {
      __hip_bfloat16 hh = __float2bfloat16(__expf(br[8 + i] - mrow));
      s += __bfloat162float(hh); o1.h[i] = hh;
    }
    lsum += s;
    *(H8*)(Bs + buf * TSZ + brow * 32 + bj) = o0;
    *(H8*)(Bs + buf * TSZ + brow * 32 + bj + 8) = o1;
  };

  stageA(0, 0); loadB(0); packB(0);
  __syncthreads();
  int cur = 0;
  for (int kt = 0; kt < 64; kt++) {
    if (kt + 1 < 64) { stageA(cur ^ 1, kt + 1); loadB(kt + 1); }
    bf16x8 af[4], bf[4];
#pragma unroll
    for (int f = 0; f < 4; f++) {
      af[f] = *(const bf16x8*)(As + cur * TSZ + (wr * 64 + f * 16 + l15) * 32 + hi * 8);
      bf[f] = *(const bf16x8*)(Bs + cur * TSZ + (wc * 64 + f * 16 + l15) * 32 + hi * 8);
    }
#pragma unroll
    for (int fm = 0; fm < 4; fm++)
#pragma unroll
      for (int fn = 0; fn < 4; fn++)
        acc[fm][fn] = __builtin_amdgcn_mfma_f32_16x16x32_bf16(af[fm], bf[fn], acc[fm][fn], 0, 0, 0);
    if (kt + 1 < 64) packB(cur ^ 1);   // writes other buffer; safe pre-barrier
    __syncthreads();
    cur ^= 1;
  }

  lred[brow][t & 1] = lsum;
  __syncthreads();

  const int row0 = blockIdx.y * 128 + wr * 64;
  const int col0 = blockIdx.x * 128 + wc * 64;
  float* Oz = O + (size_t)z * CB * NB;
  const float* Xz = X + (size_t)z * CB * NB;
#pragma unroll
  for (int fm = 0; fm < 4; fm++) {
    int rowb = row0 + fm * 16 + hi * 4;
#pragma unroll
    for (int fn = 0; fn < 4; fn++) {
      int col = col0 + fn * 16 + l15;
      int il = wc * 64 + fn * 16 + l15;
      float linv = 1.0f / (lred[il][0] + lred[il][1]);
#pragma unroll
      for (int r = 0; r < 4; r++)
        Oz[(size_t)(rowb + r) * NB + col] =
            acc[fm][fn][r] * linv + Xz[(size_t)(rowb + r) * NB + col];
    }
  }
}

// ---------------- GEMM-NT (128^2, proven): used for YT (split, hi/lo out) and V (bf16)
template <int BIAS, int EPI, int SPLIT>
__global__ __launch_bounds__(256) void gemm_nt(
    const __hip_bfloat16* __restrict__ Ah, const __hip_bfloat16* __restrict__ Al, int lda, long sA,
    const __hip_bfloat16* __restrict__ Bh, const __hip_bfloat16* __restrict__ Bl, int ldb, long sB,
    void* __restrict__ D, void* __restrict__ D2, int ldd, long sD,
    const float* __restrict__ bias, long sBias, int K) {
  constexpr int PL = SPLIT ? 4 : 2;
  constexpr int TSZ = 128 * 32;
  __shared__ alignas(16) __hip_bfloat16 sm[2 * PL * TSZ];

  const int t = threadIdx.x;
  const int z = blockIdx.z;
  const __hip_bfloat16* Ab = Ah + (size_t)z * sA + (size_t)(blockIdx.y * 128) * lda;
  const __hip_bfloat16* Bb = Bh + (size_t)z * sB + (size_t)(blockIdx.x * 128) * ldb;
  const __hip_bfloat16* Abl = SPLIT ? Al + (size_t)z * sA + (size_t)(blockIdx.y * 128) * lda : nullptr;
  const __hip_bfloat16* Bbl = SPLIT ? Bl + (size_t)z * sB + (size_t)(blockIdx.x * 128) * ldb : nullptr;
  const int wid = t >> 6, l15 = t & 15, hi = (t >> 4) & 3;
  const int wr = wid >> 1, wc = wid & 1;
  const int lineA = t >> 2, eoff = (t & 3) * 8;

  f32x4 acc[4][4] = {};

  auto stage = [&](int buf, int kt) {
    __hip_bfloat16* base = sm + buf * (PL * TSZ);
#pragma unroll
    for (int p = 0; p < 2; p++) {
      size_t goA = (size_t)(p * 64 + lineA) * lda + kt * 32 + eoff;
      size_t goB = (size_t)(p * 64 + lineA) * ldb + kt * 32 + eoff;
      int lo = p * 2048 + t * 8;
      __builtin_amdgcn_global_load_lds((const AS1 void*)(Ab + goA), (AS3 void*)(base + lo), 16, 0, 0);
      __builtin_amdgcn_global_load_lds((const AS1 void*)(Bb + goB), (AS3 void*)(base + TSZ + lo), 16, 0, 0);
      if (SPLIT) {
        __builtin_amdgcn_global_load_lds((const AS1 void*)(Abl + goA), (AS3 void*)(base + 2 * TSZ + lo), 16, 0, 0);
        __builtin_amdgcn_global_load_lds((const AS1 void*)(Bbl + goB), (AS3 void*)(base + 3 * TSZ + lo), 16, 0, 0);
      }
    }
  };

  const int nt = K >> 5;
  stage(0, 0);
  __syncthreads();
  int cur = 0;
  for (int kt = 0; kt < nt; kt++) {
    if (kt + 1 < nt) stage(cur ^ 1, kt + 1);
    const __hip_bfloat16* bb = sm + cur * (PL * TSZ);
    bf16x8 afh[4], bfh[4], afl[4], bfl[4];
#pragma unroll
    for (int f = 0; f < 4; f++) {
      int ao = (wr * 64 + f * 16 + l15) * 32 + hi * 8;
      int bo = (wc * 64 + f * 16 + l15) * 32 + hi * 8;
      afh[f] = *(const bf16x8*)(bb + ao);
      bfh[f] = *(const bf16x8*)(bb + TSZ + bo);
      if (SPLIT) { afl[f] = *(const bf16x8*)(bb + 2 * TSZ + ao); bfl[f] = *(const bf16x8*)(bb + 3 * TSZ + bo); }
    }
#pragma unroll
    for (int pass = 0; pass < (SPLIT ? 3 : 1); pass++) {
#pragma unroll
      for (int fm = 0; fm < 4; fm++)
#pragma unroll
        for (int fn = 0; fn < 4; fn++) {
          const bf16x8 a = (pass == 2) ? afl[fm] : afh[fm];
          const bf16x8 b = (pass == 1) ? bfl[fn] : bfh[fn];
          acc[fm][fn] = __builtin_amdgcn_mfma_f32_16x16x32_bf16(a, b, acc[fm][fn], 0, 0, 0);
        }
    }
    __syncthreads();
    cur ^= 1;
  }

  const int row0 = blockIdx.y * 128 + wr * 64;
  const int col0 = blockIdx.x * 128 + wc * 64;
#pragma unroll
  for (int fm = 0; fm < 4; fm++) {
    int rowb = row0 + fm * 16 + hi * 4;
#pragma unroll
    for (int fn = 0; fn < 4; fn++) {
      int col = col0 + fn * 16 + l15;
      float bc = (BIAS == 1) ? bias[(size_t)z * sBias + col] : 0.0f;
#pragma unroll
      for (int r = 0; r < 4; r++) {
        float val = acc[fm][fn][r] + bc;
        if (BIAS == 2) val += bias[(size_t)z * sBias + rowb + r];
        size_t di = (size_t)(rowb + r) * ldd + col;
        if (EPI == 1) {
          ((__hip_bfloat16*)D)[(size_t)z * sD + di] = __float2bfloat16(val);
        } else {  // EPI == 3
          __hip_bfloat16 h = __float2bfloat16(val);
          ((__hip_bfloat16*)D)[(size_t)z * sD + di] = h;
          ((__hip_bfloat16*)D2)[(size_t)z * sD + di] = __float2bfloat16(val - __bfloat162float(h));
        }
      }
    }
  }
}

// ---------------- launcher
extern "C" void kernel_launch(void* const* d_in, const int* in_sizes, int n_in,
                              void* d_out, int out_size, void* d_ws, size_t ws_size,
                              hipStream_t stream) {
  const float* x  = (const float*)d_in[0];
  const float* wq = (const float*)d_in[1];
  const float* bq = (const float*)d_in[2];
  const float* wk = (const float*)d_in[3];
  const float* wv = (const float*)d_in[5];
  const float* bv = (const float*)d_in[6];
  float* out = (float*)d_out;

  const size_t MB = 1u << 20;
  if (ws_size < 148 * MB) return;

  char* ws = (char*)d_ws;
  __hip_bfloat16* xbT_h = (__hip_bfloat16*)(ws + 0);           // [B][N][C]    16 MB
  __hip_bfloat16* xbT_l = (__hip_bfloat16*)(ws + 16 * MB);     // [B][N][C]    16 MB
  __hip_bfloat16* YT_h  = (__hip_bfloat16*)(ws + 32 * MB);     // [B][N][C]    16 MB
  __hip_bfloat16* YT_l  = (__hip_bfloat16*)(ws + 48 * MB);     // [B][N][C]    16 MB
  __hip_bfloat16* v     = (__hip_bfloat16*)(ws + 64 * MB);     // [B][C][N]    16 MB
  float*          S     = (float*)(ws + 80 * MB);              // [4][N][N]    64 MB (chunked)
  __hip_bfloat16* Gh    = (__hip_bfloat16*)(ws + 144 * MB);    // [C][C]      0.5 MB
  __hip_bfloat16* Gl    = (__hip_bfloat16*)(ws + 144 * MB + 512 * 1024);
  __hip_bfloat16* wvb   = (__hip_bfloat16*)(ws + 145 * MB);    // [C][C]      0.5 MB
  float*          u     = (float*)(ws + 145 * MB + 512 * 1024);   // [C]        2 KB
  float*          ub    = (float*)(ws + 145 * MB + 768 * 1024);   // [B][N]    64 KB
  float*          pmax  = (float*)(ws + 146 * MB);             // [4][N][32]    1 MB
  float*          rowm  = (float*)(ws + 147 * MB);             // [4][N]       32 KB

  convert_wv<<<1024, 256, 0, stream>>>(wv, wvb);
  compute_G<<<dim3(8, 8), 256, 0, stream>>>(wq, wk, Gh, Gl);
  compute_u<<<2, 256, 0, stream>>>(wk, bq, u);
  transpose_x<<<dim3(64, 16, 8), dim3(32, 8), 0, stream>>>(x, xbT_h, xbT_l);
  compute_ubias<<<BB * NB / 4, 256, 0, stream>>>(xbT_h, xbT_l, u, ub);

  // YT[b][j][c] = sum_d xbT[b][j][d] * G[c][d]   (split, hi/lo out)
  gemm_nt<0, 3, 1><<<dim3(4, 16, 8), 256, 0, stream>>>(
      xbT_h, xbT_l, CB, (long)NB * CB, Gh, Gl, CB, 0,
      YT_h, YT_l, CB, (long)NB * CB, nullptr, 0, CB);

  // v[b][c][n] = sum_cin wv[c][cin]*x[b][cin][n] + bv[c]
  gemm_nt<2, 1, 0><<<dim3(16, 4, 8), 256, 0, stream>>>(
      wvb, nullptr, CB, 0, xbT_h, nullptr, CB, (long)NB * CB,
      v, nullptr, NB, (long)CB * NB, bv, 0, CB);

  for (int c = 0; c < 2; c++) {
    size_t xoff = (size_t)c * 4 * NB * CB;
    // S + partial row-max
    gemm_s128<<<dim3(16, 16, 4), 256, 0, stream>>>(
        xbT_h + xoff, xbT_l + xoff, YT_h + xoff, YT_l + xoff,
        S, ub + (size_t)c * 4 * NB, pmax);

    reduce_rowmax<<<32, 256, 0, stream>>>(pmax, rowm);

    size_t ooff = (size_t)c * 4 * CB * NB;
    // fused exp-normalize PV + residual
    gemm_pv<<<dim3(16, 4, 4), 256, 0, stream>>>(
        v + ooff, S, rowm, x + ooff, out + ooff);
  }
}

// Round 6
// 314.650 us; speedup vs baseline: 1.3673x; 1.3673x over previous
//
#include <hip/hip_runtime.h>
#include <hip/hip_bf16.h>

typedef _Float16 half_t;
typedef _Float16 f16x8 __attribute__((ext_vector_type(8)));
typedef float f32x4 __attribute__((ext_vector_type(4)));

#define AS1 __attribute__((address_space(1)))
#define AS3 __attribute__((address_space(3)))

constexpr int CB = 512;    // channels
constexpr int NB = 2048;   // sequence length
constexpr int BB = 8;      // batch

__device__ inline f32x4 mfma16(f16x8 a, f16x8 b, f32x4 c) {
  return __builtin_amdgcn_mfma_f32_16x16x32_f16(a, b, c, 0, 0, 0);
}

// ---------------- wv -> fp16
__global__ void convert_w(const float* __restrict__ wv, half_t* __restrict__ wvh) {
  int i = blockIdx.x * 256 + threadIdx.x;
  if (i < CB * CB) wvh[i] = (half_t)wv[i];
}

// ---------------- G[c][d] = sum_o wq[o][c]*wk[o][d], fp32 accum, fp16 hi/lo out
__global__ __launch_bounds__(256) void compute_G(const float* __restrict__ wq,
                                                 const float* __restrict__ wk,
                                                 half_t* __restrict__ Gh,
                                                 half_t* __restrict__ Gl) {
  __shared__ float aq[32][65];
  __shared__ float ak[32][65];
  int c0 = blockIdx.y * 64, d0 = blockIdx.x * 64;
  int t = threadIdx.x;
  int tc = t & 15, td = t >> 4;
  float acc[4][4] = {};
  for (int o0 = 0; o0 < CB; o0 += 32) {
    __syncthreads();
    int r = t >> 3, cc = (t & 7) * 8;
#pragma unroll
    for (int i = 0; i < 8; i++) {
      aq[r][cc + i] = wq[(size_t)(o0 + r) * CB + c0 + cc + i];
      ak[r][cc + i] = wk[(size_t)(o0 + r) * CB + d0 + cc + i];
    }
    __syncthreads();
#pragma unroll 8
    for (int o = 0; o < 32; o++)
#pragma unroll
      for (int i = 0; i < 4; i++)
#pragma unroll
        for (int j = 0; j < 4; j++)
          acc[i][j] += aq[o][tc * 4 + i] * ak[o][td * 4 + j];
  }
#pragma unroll
  for (int i = 0; i < 4; i++)
#pragma unroll
    for (int j = 0; j < 4; j++) {
      int c = c0 + tc * 4 + i, d = d0 + td * 4 + j;
      float v = acc[i][j];
      half_t h = (half_t)v;
      Gh[(size_t)c * CB + d] = h;
      Gl[(size_t)c * CB + d] = (half_t)(v - (float)h);
    }
}

// ---------------- u[d] = sum_o bq[o]*wk[o][d]
__global__ void compute_u(const float* __restrict__ wk, const float* __restrict__ bq,
                          float* __restrict__ u) {
  int d = blockIdx.x * 256 + threadIdx.x;
  if (d >= CB) return;
  float s = 0.0f;
  for (int o = 0; o < CB; o++) s += bq[o] * wk[(size_t)o * CB + d];
  u[d] = s;
}

// ---------------- ubias[row] = sum_c u[c] * x[row][c]  (x = xh+xl fp16), row in [0, B*N)
__global__ __launch_bounds__(256) void compute_ubias(const half_t* __restrict__ xh,
                                                     const half_t* __restrict__ xl,
                                                     const float* __restrict__ u,
                                                     float* __restrict__ ub) {
  __shared__ float us[CB];
  for (int i = threadIdx.x; i < CB; i += 256) us[i] = u[i];
  __syncthreads();
  int row = blockIdx.x * 4 + (threadIdx.x >> 6);
  int lane = threadIdx.x & 63;
  f16x8 vh = *(const f16x8*)(xh + (size_t)row * CB + lane * 8);
  f16x8 vl = *(const f16x8*)(xl + (size_t)row * CB + lane * 8);
  float s = 0.0f;
#pragma unroll
  for (int i = 0; i < 8; i++) s += us[lane * 8 + i] * ((float)vh[i] + (float)vl[i]);
#pragma unroll
  for (int off = 32; off; off >>= 1) s += __shfl_xor(s, off);
  if (lane == 0) ub[row] = s;
}

// ---------------- x [B][C][N] fp32 -> xh/xl [B][N][C] fp16 (tiled transpose + split)
__global__ void transpose_x(const float* __restrict__ x,
                            half_t* __restrict__ oh, half_t* __restrict__ ol) {
  __shared__ float tile[32][33];
  int b = blockIdx.z, c0 = blockIdx.y * 32, n0 = blockIdx.x * 32;
  int tx = threadIdx.x, ty = threadIdx.y;          // block (32, 8)
  const float* xb = x + (size_t)b * CB * NB;
#pragma unroll
  for (int r = 0; r < 4; r++)
    tile[ty + 8 * r][tx] = xb[(size_t)(c0 + ty + 8 * r) * NB + n0 + tx];
  __syncthreads();
  size_t base = (size_t)b * NB * CB;
#pragma unroll
  for (int r = 0; r < 4; r++) {
    float v = tile[tx][ty + 8 * r];
    half_t h = (half_t)v;
    size_t idx = base + (size_t)(n0 + ty + 8 * r) * CB + c0 + tx;
    oh[idx] = h;
    ol[idx] = (half_t)(v - (float)h);
  }
}

// ---------------- GEMM-NT (proven 128^2 2-barrier, fp16):  D[M][N] = A[M][K] * B[N][K]^T
// BSPLIT: 1 -> B has hi/lo planes, 2 MFMA passes (A*Bh + A*Bl); A always 1 plane.
// BIAS: 0 none, 1 batched col-bias f32, 2 row-bias f32
// EPI: 0 f32 store; 1 fp16 store; 2 f32 store + residual R(f32); 3 fp16 hi/lo planes (D,D2)
template <int BIAS, int EPI, int BSPLIT>
__global__ __launch_bounds__(256) void gemm_nt(
    const half_t* __restrict__ A, int lda, long sA,
    const half_t* __restrict__ Bh, const half_t* __restrict__ Bl, int ldb, long sB,
    void* __restrict__ D, void* __restrict__ D2, int ldd, long sD,
    const float* __restrict__ bias, long sBias,
    const float* __restrict__ R, int ldr, long sR,
    int K) {
  constexpr int PL = 2 + BSPLIT;                 // planes: A, Bh, (Bl)
  constexpr int TSZ = 128 * 32;                  // elems per plane tile (8KB)
  __shared__ alignas(16) half_t sm[2 * PL * TSZ];

  const int t = threadIdx.x;
  const int z = blockIdx.z;
  const half_t* Ab  = A  + (size_t)z * sA + (size_t)(blockIdx.y * 128) * lda;
  const half_t* Bbh = Bh + (size_t)z * sB + (size_t)(blockIdx.x * 128) * ldb;
  const half_t* Bbl = BSPLIT ? Bl + (size_t)z * sB + (size_t)(blockIdx.x * 128) * ldb : nullptr;
  const int wid = t >> 6, l15 = t & 15, hi = (t >> 4) & 3;
  const int wr = wid >> 1, wc = wid & 1;
  const int lineA = t >> 2, eoff = (t & 3) * 8;

  f32x4 acc[4][4] = {};

  auto stage = [&](int buf, int kt) {
    half_t* base = sm + buf * (PL * TSZ);
#pragma unroll
    for (int p = 0; p < 2; p++) {
      size_t goA = (size_t)(p * 64 + lineA) * lda + kt * 32 + eoff;
      size_t goB = (size_t)(p * 64 + lineA) * ldb + kt * 32 + eoff;
      int lo = p * 2048 + t * 8;
      __builtin_amdgcn_global_load_lds((const AS1 void*)(Ab + goA),  (AS3 void*)(base + lo), 16, 0, 0);
      __builtin_amdgcn_global_load_lds((const AS1 void*)(Bbh + goB), (AS3 void*)(base + TSZ + lo), 16, 0, 0);
      if (BSPLIT)
        __builtin_amdgcn_global_load_lds((const AS1 void*)(Bbl + goB), (AS3 void*)(base + 2 * TSZ + lo), 16, 0, 0);
    }
  };

  const int nt = K >> 5;
  stage(0, 0);
  __syncthreads();
  int cur = 0;
  for (int kt = 0; kt < nt; kt++) {
    if (kt + 1 < nt) stage(cur ^ 1, kt + 1);
    const half_t* bb = sm + cur * (PL * TSZ);
    f16x8 af[4], bfh[4], bfl[4];
#pragma unroll
    for (int f = 0; f < 4; f++) {
      int ao = (wr * 64 + f * 16 + l15) * 32 + hi * 8;
      int bo = (wc * 64 + f * 16 + l15) * 32 + hi * 8;
      af[f]  = *(const f16x8*)(bb + ao);
      bfh[f] = *(const f16x8*)(bb + TSZ + bo);
      if (BSPLIT) bfl[f] = *(const f16x8*)(bb + 2 * TSZ + bo);
    }
#pragma unroll
    for (int pass = 0; pass < 1 + BSPLIT; pass++) {
#pragma unroll
      for (int fm = 0; fm < 4; fm++)
#pragma unroll
        for (int fn = 0; fn < 4; fn++)
          acc[fm][fn] = mfma16(af[fm], (pass == 1) ? bfl[fn] : bfh[fn], acc[fm][fn]);
    }
    __syncthreads();
    cur ^= 1;
  }

  const int row0 = blockIdx.y * 128 + wr * 64;
  const int col0 = blockIdx.x * 128 + wc * 64;
#pragma unroll
  for (int fm = 0; fm < 4; fm++) {
    int rowb = row0 + fm * 16 + hi * 4;
#pragma unroll
    for (int fn = 0; fn < 4; fn++) {
      int col = col0 + fn * 16 + l15;
      float bc = (BIAS == 1) ? bias[(size_t)z * sBias + col] : 0.0f;
#pragma unroll
      for (int r = 0; r < 4; r++) {
        float val = acc[fm][fn][r] + bc;
        if (BIAS == 2) val += bias[(size_t)z * sBias + rowb + r];
        size_t di = (size_t)(rowb + r) * ldd + col;
        if (EPI == 0) {
          ((float*)D)[(size_t)z * sD + di] = val;
        } else if (EPI == 1) {
          ((half_t*)D)[(size_t)z * sD + di] = (half_t)val;
        } else if (EPI == 2) {
          val += R[(size_t)z * sR + (size_t)(rowb + r) * ldr + col];
          ((float*)D)[(size_t)z * sD + di] = val;
        } else {
          half_t h = (half_t)val;
          ((half_t*)D)[(size_t)z * sD + di] = h;
          ((half_t*)D2)[(size_t)z * sD + di] = (half_t)(val - (float)h);
        }
      }
    }
  }
}

// ---------------- row softmax over S fp32 [rows][2048]; writes P fp16 in-place at row base
struct alignas(16) H8 { half_t h[8]; };

__global__ __launch_bounds__(256) void softmax_rows(float* __restrict__ S) {
  float* row = S + (size_t)blockIdx.x * NB;
  int t = threadIdx.x;
  float4 v0 = ((const float4*)row)[t * 2];
  float4 v1 = ((const float4*)row)[t * 2 + 1];
  float vals[8] = {v0.x, v0.y, v0.z, v0.w, v1.x, v1.y, v1.z, v1.w};
  float m = vals[0];
#pragma unroll
  for (int i = 1; i < 8; i++) m = fmaxf(m, vals[i]);
#pragma unroll
  for (int off = 32; off; off >>= 1) m = fmaxf(m, __shfl_xor(m, off));
  __shared__ float redm[4], reds[4];
  if ((t & 63) == 0) redm[t >> 6] = m;
  __syncthreads();
  m = fmaxf(fmaxf(redm[0], redm[1]), fmaxf(redm[2], redm[3]));
  float e[8], s = 0.0f;
#pragma unroll
  for (int i = 0; i < 8; i++) { e[i] = __expf(vals[i] - m); s += e[i]; }
#pragma unroll
  for (int off = 32; off; off >>= 1) s += __shfl_xor(s, off);
  if ((t & 63) == 0) reds[t >> 6] = s;
  __syncthreads();
  s = reds[0] + reds[1] + reds[2] + reds[3];
  float inv = 1.0f / s;
  H8 ob;
#pragma unroll
  for (int i = 0; i < 8; i++) ob.h[i] = (half_t)(e[i] * inv);
  // all reads of this row happened before the first __syncthreads; safe in-place overlay
  *reinterpret_cast<H8*>(reinterpret_cast<char*>(row) + t * 16) = ob;
}

// ---------------- launcher
extern "C" void kernel_launch(void* const* d_in, const int* in_sizes, int n_in,
                              void* d_out, int out_size, void* d_ws, size_t ws_size,
                              hipStream_t stream) {
  const float* x  = (const float*)d_in[0];
  const float* wq = (const float*)d_in[1];
  const float* bq = (const float*)d_in[2];
  const float* wk = (const float*)d_in[3];
  const float* wv = (const float*)d_in[5];
  const float* bv = (const float*)d_in[6];
  float* out = (float*)d_out;

  const size_t MB = 1u << 20;
  if (ws_size < 147 * MB) return;

  char* ws = (char*)d_ws;
  half_t* xh   = (half_t*)(ws + 0);            // [B][N][C]    16 MB
  half_t* xl   = (half_t*)(ws + 16 * MB);      // [B][N][C]    16 MB
  half_t* YTh  = (half_t*)(ws + 32 * MB);      // [B][N][C]    16 MB
  half_t* YTl  = (half_t*)(ws + 48 * MB);      // [B][N][C]    16 MB
  half_t* v    = (half_t*)(ws + 64 * MB);      // [B][C][N]    16 MB
  float*  S    = (float*)(ws + 80 * MB);       // [4][N][N]    64 MB (chunked)
  half_t* Gh   = (half_t*)(ws + 144 * MB);     // [C][C]      0.5 MB
  half_t* Gl   = (half_t*)(ws + 144 * MB + 512 * 1024);
  half_t* wvh  = (half_t*)(ws + 145 * MB);     // [C][C]      0.5 MB
  float*  u    = (float*)(ws + 145 * MB + 512 * 1024);   // [C]      2 KB
  float*  ub   = (float*)(ws + 145 * MB + 768 * 1024);   // [B][N]  64 KB

  convert_w<<<1024, 256, 0, stream>>>(wv, wvh);
  compute_G<<<dim3(8, 8), 256, 0, stream>>>(wq, wk, Gh, Gl);
  compute_u<<<2, 256, 0, stream>>>(wk, bq, u);
  transpose_x<<<dim3(64, 16, 8), dim3(32, 8), 0, stream>>>(x, xh, xl);
  compute_ubias<<<BB * NB / 4, 256, 0, stream>>>(xh, xl, u, ub);

  // YT[b][j][c] = sum_d xh[b][j][d] * G[c][d]   (B-split fp16, hi/lo out)
  gemm_nt<0, 3, 1><<<dim3(4, 16, 8), 256, 0, stream>>>(
      xh, CB, (long)NB * CB, Gh, Gl, CB, 0,
      YTh, YTl, CB, (long)NB * CB, nullptr, 0, nullptr, 0, 0, CB);

  // v[b][c][n] = sum_cin wv[c][cin]*x[b][cin][n] + bv[c]   (plain fp16)
  gemm_nt<2, 1, 0><<<dim3(16, 4, 8), 256, 0, stream>>>(
      wvh, CB, 0, xh, nullptr, CB, (long)NB * CB,
      v, nullptr, NB, (long)CB * NB, bv, 0, nullptr, 0, 0, CB);

  for (int c = 0; c < 2; c++) {
    size_t xoff = (size_t)c * 4 * NB * CB;
    // S[z][i][j] = sum_c xh[i][c]*YT[j][c] + ub[z][j]   (B-split fp16, f32 out)
    gemm_nt<1, 0, 1><<<dim3(16, 16, 4), 256, 0, stream>>>(
        xh + xoff, CB, (long)NB * CB,
        YTh + xoff, YTl + xoff, CB, (long)NB * CB,
        S, nullptr, NB, (long)NB * NB, ub + (size_t)c * 4 * NB, NB, nullptr, 0, 0, CB);

    softmax_rows<<<4 * NB, 256, 0, stream>>>(S);

    size_t ooff = (size_t)c * 4 * CB * NB;
    // out[z][ch][i] = sum_j v[z][ch][j]*P[z][i][j] + x[z][ch][i]   (P fp16 overlay, ld=4096)
    gemm_nt<0, 2, 0><<<dim3(16, 4, 4), 256, 0, stream>>>(
        v + ooff, NB, (long)CB * NB,
        (const half_t*)S, nullptr, 2 * NB, (long)NB * 2 * NB,
        out + ooff, nullptr, NB, (long)CB * NB, nullptr, 0,
        x + ooff, NB, (long)CB * NB, NB);
  }
}

// Round 7
// 280.408 us; speedup vs baseline: 1.5343x; 1.1221x over previous
//
#include <hip/hip_runtime.h>
#include <hip/hip_bf16.h>

typedef _Float16 half_t;
typedef _Float16 f16x8 __attribute__((ext_vector_type(8)));
typedef float f32x4 __attribute__((ext_vector_type(4)));

#define AS1 __attribute__((address_space(1)))
#define AS3 __attribute__((address_space(3)))

constexpr int CB = 512;    // channels
constexpr int NB = 2048;   // sequence length
constexpr int BB = 8;      // batch

__device__ inline f32x4 mfma16(f16x8 a, f16x8 b, f32x4 c) {
  return __builtin_amdgcn_mfma_f32_16x16x32_f16(a, b, c, 0, 0, 0);
}

// ---------------- wv -> fp16
__global__ void convert_w(const float* __restrict__ wv, half_t* __restrict__ wvh) {
  int i = blockIdx.x * 256 + threadIdx.x;
  if (i < CB * CB) wvh[i] = (half_t)wv[i];
}

// ---------------- G partials: Gp[z][c][d] = sum_{o in chunk z} wq[o][c]*wk[o][d]
// grid (8,8,8): 64x64 output tile, 64-deep K chunk. float4 LDS reads, stride-68 pad.
__global__ __launch_bounds__(256) void compute_G_part(const float* __restrict__ wq,
                                                      const float* __restrict__ wk,
                                                      float* __restrict__ Gp) {
  __shared__ float aq[64][68];
  __shared__ float ak[64][68];
  const int c0 = blockIdx.y * 64, d0 = blockIdx.x * 64, o0 = blockIdx.z * 64;
  const int t = threadIdx.x;
  // stage: each thread 16 consecutive floats per tile (row t>>2, cols (t&3)*16..+15)
  {
    const int r = t >> 2, cbase = (t & 3) * 16;
    const float* q = wq + (size_t)(o0 + r) * CB + c0 + cbase;
    const float* k = wk + (size_t)(o0 + r) * CB + d0 + cbase;
#pragma unroll
    for (int q4 = 0; q4 < 4; q4++) {
      *(float4*)&aq[r][cbase + q4 * 4] = *(const float4*)(q + q4 * 4);
      *(float4*)&ak[r][cbase + q4 * 4] = *(const float4*)(k + q4 * 4);
    }
  }
  __syncthreads();
  const int tc = t & 15, td = t >> 4;
  float acc[4][4] = {};
#pragma unroll 8
  for (int o = 0; o < 64; o++) {
    float4 a4 = *(const float4*)&aq[o][tc * 4];
    float4 b4 = *(const float4*)&ak[o][td * 4];
    float av[4] = {a4.x, a4.y, a4.z, a4.w};
    float bv[4] = {b4.x, b4.y, b4.z, b4.w};
#pragma unroll
    for (int i = 0; i < 4; i++)
#pragma unroll
      for (int j = 0; j < 4; j++)
        acc[i][j] += av[i] * bv[j];
  }
  float* gz = Gp + (size_t)blockIdx.z * CB * CB;
#pragma unroll
  for (int i = 0; i < 4; i++) {
    int c = c0 + tc * 4 + i;
#pragma unroll
    for (int j = 0; j < 4; j++)
      gz[(size_t)c * CB + d0 + td * 4 + j] = acc[i][j];
  }
}

// ---------------- reduce 8 partials -> G hi/lo fp16
__global__ void reduce_G(const float* __restrict__ Gp,
                         half_t* __restrict__ Gh, half_t* __restrict__ Gl) {
  int i = blockIdx.x * 256 + threadIdx.x;   // 1024 blocks cover 512*512
  if (i >= CB * CB) return;
  float s = 0.0f;
#pragma unroll
  for (int z = 0; z < 8; z++) s += Gp[(size_t)z * CB * CB + i];
  half_t h = (half_t)s;
  Gh[i] = h;
  Gl[i] = (half_t)(s - (float)h);
}

// ---------------- u[d] = sum_o bq[o]*wk[o][d]
__global__ void compute_u(const float* __restrict__ wk, const float* __restrict__ bq,
                          float* __restrict__ u) {
  int d = blockIdx.x * 256 + threadIdx.x;
  if (d >= CB) return;
  float s = 0.0f;
  for (int o = 0; o < CB; o++) s += bq[o] * wk[(size_t)o * CB + d];
  u[d] = s;
}

// ---------------- ubias[row] = sum_c u[c] * x[row][c]  (x = xh+xl fp16), row in [0, B*N)
__global__ __launch_bounds__(256) void compute_ubias(const half_t* __restrict__ xh,
                                                     const half_t* __restrict__ xl,
                                                     const float* __restrict__ u,
                                                     float* __restrict__ ub) {
  __shared__ float us[CB];
  for (int i = threadIdx.x; i < CB; i += 256) us[i] = u[i];
  __syncthreads();
  int row = blockIdx.x * 4 + (threadIdx.x >> 6);
  int lane = threadIdx.x & 63;
  f16x8 vh = *(const f16x8*)(xh + (size_t)row * CB + lane * 8);
  f16x8 vl = *(const f16x8*)(xl + (size_t)row * CB + lane * 8);
  float s = 0.0f;
#pragma unroll
  for (int i = 0; i < 8; i++) s += us[lane * 8 + i] * ((float)vh[i] + (float)vl[i]);
#pragma unroll
  for (int off = 32; off; off >>= 1) s += __shfl_xor(s, off);
  if (lane == 0) ub[row] = s;
}

// ---------------- x [B][C][N] fp32 -> xh/xl [B][N][C] fp16 (tiled transpose + split)
__global__ void transpose_x(const float* __restrict__ x,
                            half_t* __restrict__ oh, half_t* __restrict__ ol) {
  __shared__ float tile[32][33];
  int b = blockIdx.z, c0 = blockIdx.y * 32, n0 = blockIdx.x * 32;
  int tx = threadIdx.x, ty = threadIdx.y;          // block (32, 8)
  const float* xb = x + (size_t)b * CB * NB;
#pragma unroll
  for (int r = 0; r < 4; r++)
    tile[ty + 8 * r][tx] = xb[(size_t)(c0 + ty + 8 * r) * NB + n0 + tx];
  __syncthreads();
  size_t base = (size_t)b * NB * CB;
#pragma unroll
  for (int r = 0; r < 4; r++) {
    float v = tile[tx][ty + 8 * r];
    half_t h = (half_t)v;
    size_t idx = base + (size_t)(n0 + ty + 8 * r) * CB + c0 + tx;
    oh[idx] = h;
    ol[idx] = (half_t)(v - (float)h);
  }
}

// ---------------- GEMM-NT (proven 128^2 2-barrier, fp16):  D[M][N] = A[M][K] * B[N][K]^T
// BSPLIT: 1 -> B has hi/lo planes, 2 MFMA passes (A*Bh + A*Bl); A always 1 plane.
// BIAS: 0 none, 1 batched col-bias f32, 2 row-bias f32
// EPI: 0 f32 store; 1 fp16 store; 2 f32 store + residual R(f32); 3 fp16 hi/lo planes (D,D2)
template <int BIAS, int EPI, int BSPLIT>
__global__ __launch_bounds__(256) void gemm_nt(
    const half_t* __restrict__ A, int lda, long sA,
    const half_t* __restrict__ Bh, const half_t* __restrict__ Bl, int ldb, long sB,
    void* __restrict__ D, void* __restrict__ D2, int ldd, long sD,
    const float* __restrict__ bias, long sBias,
    const float* __restrict__ R, int ldr, long sR,
    int K) {
  constexpr int PL = 2 + BSPLIT;                 // planes: A, Bh, (Bl)
  constexpr int TSZ = 128 * 32;                  // elems per plane tile (8KB)
  __shared__ alignas(16) half_t sm[2 * PL * TSZ];

  const int t = threadIdx.x;
  const int z = blockIdx.z;
  const half_t* Ab  = A  + (size_t)z * sA + (size_t)(blockIdx.y * 128) * lda;
  const half_t* Bbh = Bh + (size_t)z * sB + (size_t)(blockIdx.x * 128) * ldb;
  const half_t* Bbl = BSPLIT ? Bl + (size_t)z * sB + (size_t)(blockIdx.x * 128) * ldb : nullptr;
  const int wid = t >> 6, l15 = t & 15, hi = (t >> 4) & 3;
  const int wr = wid >> 1, wc = wid & 1;
  const int lineA = t >> 2, eoff = (t & 3) * 8;

  f32x4 acc[4][4] = {};

  auto stage = [&](int buf, int kt) {
    half_t* base = sm + buf * (PL * TSZ);
#pragma unroll
    for (int p = 0; p < 2; p++) {
      size_t goA = (size_t)(p * 64 + lineA) * lda + kt * 32 + eoff;
      size_t goB = (size_t)(p * 64 + lineA) * ldb + kt * 32 + eoff;
      int lo = p * 2048 + t * 8;
      __builtin_amdgcn_global_load_lds((const AS1 void*)(Ab + goA),  (AS3 void*)(base + lo), 16, 0, 0);
      __builtin_amdgcn_global_load_lds((const AS1 void*)(Bbh + goB), (AS3 void*)(base + TSZ + lo), 16, 0, 0);
      if (BSPLIT)
        __builtin_amdgcn_global_load_lds((const AS1 void*)(Bbl + goB), (AS3 void*)(base + 2 * TSZ + lo), 16, 0, 0);
    }
  };

  const int nt = K >> 5;
  stage(0, 0);
  __syncthreads();
  int cur = 0;
  for (int kt = 0; kt < nt; kt++) {
    if (kt + 1 < nt) stage(cur ^ 1, kt + 1);
    const half_t* bb = sm + cur * (PL * TSZ);
    f16x8 af[4], bfh[4], bfl[4];
#pragma unroll
    for (int f = 0; f < 4; f++) {
      int ao = (wr * 64 + f * 16 + l15) * 32 + hi * 8;
      int bo = (wc * 64 + f * 16 + l15) * 32 + hi * 8;
      af[f]  = *(const f16x8*)(bb + ao);
      bfh[f] = *(const f16x8*)(bb + TSZ + bo);
      if (BSPLIT) bfl[f] = *(const f16x8*)(bb + 2 * TSZ + bo);
    }
#pragma unroll
    for (int pass = 0; pass < 1 + BSPLIT; pass++) {
#pragma unroll
      for (int fm = 0; fm < 4; fm++)
#pragma unroll
        for (int fn = 0; fn < 4; fn++)
          acc[fm][fn] = mfma16(af[fm], (pass == 1) ? bfl[fn] : bfh[fn], acc[fm][fn]);
    }
    __syncthreads();
    cur ^= 1;
  }

  const int row0 = blockIdx.y * 128 + wr * 64;
  const int col0 = blockIdx.x * 128 + wc * 64;
#pragma unroll
  for (int fm = 0; fm < 4; fm++) {
    int rowb = row0 + fm * 16 + hi * 4;
#pragma unroll
    for (int fn = 0; fn < 4; fn++) {
      int col = col0 + fn * 16 + l15;
      float bc = (BIAS == 1) ? bias[(size_t)z * sBias + col] : 0.0f;
#pragma unroll
      for (int r = 0; r < 4; r++) {
        float val = acc[fm][fn][r] + bc;
        if (BIAS == 2) val += bias[(size_t)z * sBias + rowb + r];
        size_t di = (size_t)(rowb + r) * ldd + col;
        if (EPI == 0) {
          ((float*)D)[(size_t)z * sD + di] = val;
        } else if (EPI == 1) {
          ((half_t*)D)[(size_t)z * sD + di] = (half_t)val;
        } else if (EPI == 2) {
          val += R[(size_t)z * sR + (size_t)(rowb + r) * ldr + col];
          ((float*)D)[(size_t)z * sD + di] = val;
        } else {
          half_t h = (half_t)val;
          ((half_t*)D)[(size_t)z * sD + di] = h;
          ((half_t*)D2)[(size_t)z * sD + di] = (half_t)(val - (float)h);
        }
      }
    }
  }
}

// ---------------- row softmax over S fp32 [rows][2048]; writes P fp16 in-place at row base
struct alignas(16) H8 { half_t h[8]; };

__global__ __launch_bounds__(256) void softmax_rows(float* __restrict__ S) {
  float* row = S + (size_t)blockIdx.x * NB;
  int t = threadIdx.x;
  float4 v0 = ((const float4*)row)[t * 2];
  float4 v1 = ((const float4*)row)[t * 2 + 1];
  float vals[8] = {v0.x, v0.y, v0.z, v0.w, v1.x, v1.y, v1.z, v1.w};
  float m = vals[0];
#pragma unroll
  for (int i = 1; i < 8; i++) m = fmaxf(m, vals[i]);
#pragma unroll
  for (int off = 32; off; off >>= 1) m = fmaxf(m, __shfl_xor(m, off));
  __shared__ float redm[4], reds[4];
  if ((t & 63) == 0) redm[t >> 6] = m;
  __syncthreads();
  m = fmaxf(fmaxf(redm[0], redm[1]), fmaxf(redm[2], redm[3]));
  float e[8], s = 0.0f;
#pragma unroll
  for (int i = 0; i < 8; i++) { e[i] = __expf(vals[i] - m); s += e[i]; }
#pragma unroll
  for (int off = 32; off; off >>= 1) s += __shfl_xor(s, off);
  if ((t & 63) == 0) reds[t >> 6] = s;
  __syncthreads();
  s = reds[0] + reds[1] + reds[2] + reds[3];
  float inv = 1.0f / s;
  H8 ob;
#pragma unroll
  for (int i = 0; i < 8; i++) ob.h[i] = (half_t)(e[i] * inv);
  // all reads of this row happened before the first __syncthreads; safe in-place overlay
  *reinterpret_cast<H8*>(reinterpret_cast<char*>(row) + t * 16) = ob;
}

// ---------------- launcher
extern "C" void kernel_launch(void* const* d_in, const int* in_sizes, int n_in,
                              void* d_out, int out_size, void* d_ws, size_t ws_size,
                              hipStream_t stream) {
  const float* x  = (const float*)d_in[0];
  const float* wq = (const float*)d_in[1];
  const float* bq = (const float*)d_in[2];
  const float* wk = (const float*)d_in[3];
  const float* wv = (const float*)d_in[5];
  const float* bv = (const float*)d_in[6];
  float* out = (float*)d_out;

  const size_t MB = 1u << 20;
  if (ws_size < 147 * MB) return;

  char* ws = (char*)d_ws;
  half_t* xh   = (half_t*)(ws + 0);            // [B][N][C]    16 MB
  half_t* xl   = (half_t*)(ws + 16 * MB);      // [B][N][C]    16 MB
  half_t* YTh  = (half_t*)(ws + 32 * MB);      // [B][N][C]    16 MB
  half_t* YTl  = (half_t*)(ws + 48 * MB);      // [B][N][C]    16 MB
  half_t* v    = (half_t*)(ws + 64 * MB);      // [B][C][N]    16 MB
  float*  S    = (float*)(ws + 80 * MB);       // [4][N][N]    64 MB (chunked)
  float*  Gp   = (float*)(ws + 80 * MB);       // [8][C][C]     8 MB (overlay; dead before S)
  half_t* Gh   = (half_t*)(ws + 144 * MB);     // [C][C]      0.5 MB
  half_t* Gl   = (half_t*)(ws + 144 * MB + 512 * 1024);
  half_t* wvh  = (half_t*)(ws + 145 * MB);     // [C][C]      0.5 MB
  float*  u    = (float*)(ws + 145 * MB + 512 * 1024);   // [C]      2 KB
  float*  ub   = (float*)(ws + 145 * MB + 768 * 1024);   // [B][N]  64 KB

  convert_w<<<1024, 256, 0, stream>>>(wv, wvh);
  compute_G_part<<<dim3(8, 8, 8), 256, 0, stream>>>(wq, wk, Gp);
  reduce_G<<<1024, 256, 0, stream>>>(Gp, Gh, Gl);
  compute_u<<<2, 256, 0, stream>>>(wk, bq, u);
  transpose_x<<<dim3(64, 16, 8), dim3(32, 8), 0, stream>>>(x, xh, xl);
  compute_ubias<<<BB * NB / 4, 256, 0, stream>>>(xh, xl, u, ub);

  // YT[b][j][c] = sum_d xh[b][j][d] * G[c][d]   (B-split fp16, hi/lo out)
  gemm_nt<0, 3, 1><<<dim3(4, 16, 8), 256, 0, stream>>>(
      xh, CB, (long)NB * CB, Gh, Gl, CB, 0,
      YTh, YTl, CB, (long)NB * CB, nullptr, 0, nullptr, 0, 0, CB);

  // v[b][c][n] = sum_cin wv[c][cin]*x[b][cin][n] + bv[c]   (plain fp16)
  gemm_nt<2, 1, 0><<<dim3(16, 4, 8), 256, 0, stream>>>(
      wvh, CB, 0, xh, nullptr, CB, (long)NB * CB,
      v, nullptr, NB, (long)CB * NB, bv, 0, nullptr, 0, 0, CB);

  for (int c = 0; c < 2; c++) {
    size_t xoff = (size_t)c * 4 * NB * CB;
    // S[z][i][j] = sum_c xh[i][c]*YT[j][c] + ub[z][j]   (B-split fp16, f32 out)
    gemm_nt<1, 0, 1><<<dim3(16, 16, 4), 256, 0, stream>>>(
        xh + xoff, CB, (long)NB * CB,
        YTh + xoff, YTl + xoff, CB, (long)NB * CB,
        S, nullptr, NB, (long)NB * NB, ub + (size_t)c * 4 * NB, NB, nullptr, 0, 0, CB);

    softmax_rows<<<4 * NB, 256, 0, stream>>>(S);

    size_t ooff = (size_t)c * 4 * CB * NB;
    // out[z][ch][i] = sum_j v[z][ch][j]*P[z][i][j] + x[z][ch][i]   (P fp16 overlay, ld=4096)
    gemm_nt<0, 2, 0><<<dim3(16, 4, 4), 256, 0, stream>>>(
        v + ooff, NB, (long)CB * NB,
        (const half_t*)S, nullptr, 2 * NB, (long)NB * 2 * NB,
        out + ooff, nullptr, NB, (long)CB * NB, nullptr, 0,
        x + ooff, NB, (long)CB * NB, NB);
  }
}

// Round 8
// 259.254 us; speedup vs baseline: 1.6595x; 1.0816x over previous
//
#include <hip/hip_runtime.h>
#include <hip/hip_bf16.h>

typedef _Float16 half_t;
typedef _Float16 f16x8 __attribute__((ext_vector_type(8)));
typedef float f32x4 __attribute__((ext_vector_type(4)));

#define AS1 __attribute__((address_space(1)))
#define AS3 __attribute__((address_space(3)))

constexpr int CB = 512;    // channels
constexpr int NB = 2048;   // sequence length
constexpr int BB = 8;      // batch

__device__ inline f32x4 mfma16(f16x8 a, f16x8 b, f32x4 c) {
  return __builtin_amdgcn_mfma_f32_16x16x32_f16(a, b, c, 0, 0, 0);
}

// ---------------- wv -> fp16
__global__ void convert_w(const float* __restrict__ wv, half_t* __restrict__ wvh) {
  int i = blockIdx.x * 256 + threadIdx.x;
  if (i < CB * CB) wvh[i] = (half_t)wv[i];
}

// ---------------- G partials: Gp[z][c][d] = sum_{o in chunk z} wq[o][c]*wk[o][d]
__global__ __launch_bounds__(256) void compute_G_part(const float* __restrict__ wq,
                                                      const float* __restrict__ wk,
                                                      float* __restrict__ Gp) {
  __shared__ float aq[64][68];
  __shared__ float ak[64][68];
  const int c0 = blockIdx.y * 64, d0 = blockIdx.x * 64, o0 = blockIdx.z * 64;
  const int t = threadIdx.x;
  {
    const int r = t >> 2, cbase = (t & 3) * 16;
    const float* q = wq + (size_t)(o0 + r) * CB + c0 + cbase;
    const float* k = wk + (size_t)(o0 + r) * CB + d0 + cbase;
#pragma unroll
    for (int q4 = 0; q4 < 4; q4++) {
      *(float4*)&aq[r][cbase + q4 * 4] = *(const float4*)(q + q4 * 4);
      *(float4*)&ak[r][cbase + q4 * 4] = *(const float4*)(k + q4 * 4);
    }
  }
  __syncthreads();
  const int tc = t & 15, td = t >> 4;
  float acc[4][4] = {};
#pragma unroll 8
  for (int o = 0; o < 64; o++) {
    float4 a4 = *(const float4*)&aq[o][tc * 4];
    float4 b4 = *(const float4*)&ak[o][td * 4];
    float av[4] = {a4.x, a4.y, a4.z, a4.w};
    float bv[4] = {b4.x, b4.y, b4.z, b4.w};
#pragma unroll
    for (int i = 0; i < 4; i++)
#pragma unroll
      for (int j = 0; j < 4; j++)
        acc[i][j] += av[i] * bv[j];
  }
  float* gz = Gp + (size_t)blockIdx.z * CB * CB;
#pragma unroll
  for (int i = 0; i < 4; i++) {
    int c = c0 + tc * 4 + i;
#pragma unroll
    for (int j = 0; j < 4; j++)
      gz[(size_t)c * CB + d0 + td * 4 + j] = acc[i][j];
  }
}

// ---------------- reduce 8 partials -> G hi/lo fp16
__global__ void reduce_G(const float* __restrict__ Gp,
                         half_t* __restrict__ Gh, half_t* __restrict__ Gl) {
  int i = blockIdx.x * 256 + threadIdx.x;
  if (i >= CB * CB) return;
  float s = 0.0f;
#pragma unroll
  for (int z = 0; z < 8; z++) s += Gp[(size_t)z * CB * CB + i];
  half_t h = (half_t)s;
  Gh[i] = h;
  Gl[i] = (half_t)(s - (float)h);
}

// ---------------- u[d] = sum_o bq[o]*wk[o][d]
__global__ void compute_u(const float* __restrict__ wk, const float* __restrict__ bq,
                          float* __restrict__ u) {
  int d = blockIdx.x * 256 + threadIdx.x;
  if (d >= CB) return;
  float s = 0.0f;
  for (int o = 0; o < CB; o++) s += bq[o] * wk[(size_t)o * CB + d];
  u[d] = s;
}

// ---------------- ubias[row] = sum_c u[c] * xh[row][c], row in [0, B*N)
__global__ __launch_bounds__(256) void compute_ubias(const half_t* __restrict__ xh,
                                                     const float* __restrict__ u,
                                                     float* __restrict__ ub) {
  __shared__ float us[CB];
  for (int i = threadIdx.x; i < CB; i += 256) us[i] = u[i];
  __syncthreads();
  int row = blockIdx.x * 4 + (threadIdx.x >> 6);
  int lane = threadIdx.x & 63;
  f16x8 vh = *(const f16x8*)(xh + (size_t)row * CB + lane * 8);
  float s = 0.0f;
#pragma unroll
  for (int i = 0; i < 8; i++) s += us[lane * 8 + i] * (float)vh[i];
#pragma unroll
  for (int off = 32; off; off >>= 1) s += __shfl_xor(s, off);
  if (lane == 0) ub[row] = s;
}

// ---------------- x [B][C][N] fp32 -> xh [B][N][C] fp16 (tiled transpose)
__global__ void transpose_x(const float* __restrict__ x, half_t* __restrict__ oh) {
  __shared__ float tile[32][33];
  int b = blockIdx.z, c0 = blockIdx.y * 32, n0 = blockIdx.x * 32;
  int tx = threadIdx.x, ty = threadIdx.y;          // block (32, 8)
  const float* xb = x + (size_t)b * CB * NB;
#pragma unroll
  for (int r = 0; r < 4; r++)
    tile[ty + 8 * r][tx] = xb[(size_t)(c0 + ty + 8 * r) * NB + n0 + tx];
  __syncthreads();
  size_t base = (size_t)b * NB * CB;
#pragma unroll
  for (int r = 0; r < 4; r++)
    oh[base + (size_t)(n0 + ty + 8 * r) * CB + c0 + tx] = (half_t)tile[tx][ty + 8 * r];
}

// ---------------- GEMM-NT (proven 128^2 2-barrier, fp16):  D[M][N] = A[M][K] * B[N][K]^T
// BSPLIT: 1 -> B has hi/lo planes, 2 MFMA passes (A*Bh + A*Bl); A always 1 plane.
// BIAS: 0 none, 1 batched col-bias f32, 2 row-bias f32
// EPI: 0 f32 store; 1 fp16 store; 2 f32 store + residual R(f32)
template <int BIAS, int EPI, int BSPLIT>
__global__ __launch_bounds__(256) void gemm_nt(
    const half_t* __restrict__ A, int lda, long sA,
    const half_t* __restrict__ Bh, const half_t* __restrict__ Bl, int ldb, long sB,
    void* __restrict__ D, int ldd, long sD,
    const float* __restrict__ bias, long sBias,
    const float* __restrict__ R, int ldr, long sR,
    int K) {
  constexpr int PL = 2 + BSPLIT;                 // planes: A, Bh, (Bl)
  constexpr int TSZ = 128 * 32;                  // elems per plane tile (8KB)
  __shared__ alignas(16) half_t sm[2 * PL * TSZ];

  const int t = threadIdx.x;
  const int z = blockIdx.z;
  const half_t* Ab  = A  + (size_t)z * sA + (size_t)(blockIdx.y * 128) * lda;
  const half_t* Bbh = Bh + (size_t)z * sB + (size_t)(blockIdx.x * 128) * ldb;
  const half_t* Bbl = BSPLIT ? Bl + (size_t)z * sB + (size_t)(blockIdx.x * 128) * ldb : nullptr;
  const int wid = t >> 6, l15 = t & 15, hi = (t >> 4) & 3;
  const int wr = wid >> 1, wc = wid & 1;
  const int lineA = t >> 2, eoff = (t & 3) * 8;

  f32x4 acc[4][4] = {};

  auto stage = [&](int buf, int kt) {
    half_t* base = sm + buf * (PL * TSZ);
#pragma unroll
    for (int p = 0; p < 2; p++) {
      size_t goA = (size_t)(p * 64 + lineA) * lda + kt * 32 + eoff;
      size_t goB = (size_t)(p * 64 + lineA) * ldb + kt * 32 + eoff;
      int lo = p * 2048 + t * 8;
      __builtin_amdgcn_global_load_lds((const AS1 void*)(Ab + goA),  (AS3 void*)(base + lo), 16, 0, 0);
      __builtin_amdgcn_global_load_lds((const AS1 void*)(Bbh + goB), (AS3 void*)(base + TSZ + lo), 16, 0, 0);
      if (BSPLIT)
        __builtin_amdgcn_global_load_lds((const AS1 void*)(Bbl + goB), (AS3 void*)(base + 2 * TSZ + lo), 16, 0, 0);
    }
  };

  const int nt = K >> 5;
  stage(0, 0);
  __syncthreads();
  int cur = 0;
  for (int kt = 0; kt < nt; kt++) {
    if (kt + 1 < nt) stage(cur ^ 1, kt + 1);
    const half_t* bb = sm + cur * (PL * TSZ);
    f16x8 af[4], bfh[4], bfl[4];
#pragma unroll
    for (int f = 0; f < 4; f++) {
      int ao = (wr * 64 + f * 16 + l15) * 32 + hi * 8;
      int bo = (wc * 64 + f * 16 + l15) * 32 + hi * 8;
      af[f]  = *(const f16x8*)(bb + ao);
      bfh[f] = *(const f16x8*)(bb + TSZ + bo);
      if (BSPLIT) bfl[f] = *(const f16x8*)(bb + 2 * TSZ + bo);
    }
#pragma unroll
    for (int pass = 0; pass < 1 + BSPLIT; pass++) {
#pragma unroll
      for (int fm = 0; fm < 4; fm++)
#pragma unroll
        for (int fn = 0; fn < 4; fn++)
          acc[fm][fn] = mfma16(af[fm], (pass == 1) ? bfl[fn] : bfh[fn], acc[fm][fn]);
    }
    __syncthreads();
    cur ^= 1;
  }

  const int row0 = blockIdx.y * 128 + wr * 64;
  const int col0 = blockIdx.x * 128 + wc * 64;
#pragma unroll
  for (int fm = 0; fm < 4; fm++) {
    int rowb = row0 + fm * 16 + hi * 4;
#pragma unroll
    for (int fn = 0; fn < 4; fn++) {
      int col = col0 + fn * 16 + l15;
      float bc = (BIAS == 1) ? bias[(size_t)z * sBias + col] : 0.0f;
#pragma unroll
      for (int r = 0; r < 4; r++) {
        float val = acc[fm][fn][r] + bc;
        if (BIAS == 2) val += bias[(size_t)z * sBias + rowb + r];
        size_t di = (size_t)(rowb + r) * ldd + col;
        if (EPI == 0) {
          ((float*)D)[(size_t)z * sD + di] = val;
        } else if (EPI == 1) {
          ((half_t*)D)[(size_t)z * sD + di] = (half_t)val;
        } else {  // EPI == 2
          val += R[(size_t)z * sR + (size_t)(rowb + r) * ldr + col];
          ((float*)D)[(size_t)z * sD + di] = val;
        }
      }
    }
  }
}

// ---------------- row softmax over S fp32 [rows][2048]; writes P fp16 in-place at row base
struct alignas(16) H8 { half_t h[8]; };

__global__ __launch_bounds__(256) void softmax_rows(float* __restrict__ S) {
  float* row = S + (size_t)blockIdx.x * NB;
  int t = threadIdx.x;
  float4 v0 = ((const float4*)row)[t * 2];
  float4 v1 = ((const float4*)row)[t * 2 + 1];
  float vals[8] = {v0.x, v0.y, v0.z, v0.w, v1.x, v1.y, v1.z, v1.w};
  float m = vals[0];
#pragma unroll
  for (int i = 1; i < 8; i++) m = fmaxf(m, vals[i]);
#pragma unroll
  for (int off = 32; off; off >>= 1) m = fmaxf(m, __shfl_xor(m, off));
  __shared__ float redm[4], reds[4];
  if ((t & 63) == 0) redm[t >> 6] = m;
  __syncthreads();
  m = fmaxf(fmaxf(redm[0], redm[1]), fmaxf(redm[2], redm[3]));
  float e[8], s = 0.0f;
#pragma unroll
  for (int i = 0; i < 8; i++) { e[i] = __expf(vals[i] - m); s += e[i]; }
#pragma unroll
  for (int off = 32; off; off >>= 1) s += __shfl_xor(s, off);
  if ((t & 63) == 0) reds[t >> 6] = s;
  __syncthreads();
  s = reds[0] + reds[1] + reds[2] + reds[3];
  float inv = 1.0f / s;
  H8 ob;
#pragma unroll
  for (int i = 0; i < 8; i++) ob.h[i] = (half_t)(e[i] * inv);
  *reinterpret_cast<H8*>(reinterpret_cast<char*>(row) + t * 16) = ob;
}

// ---------------- launcher
extern "C" void kernel_launch(void* const* d_in, const int* in_sizes, int n_in,
                              void* d_out, int out_size, void* d_ws, size_t ws_size,
                              hipStream_t stream) {
  const float* x  = (const float*)d_in[0];
  const float* wq = (const float*)d_in[1];
  const float* bq = (const float*)d_in[2];
  const float* wk = (const float*)d_in[3];
  const float* wv = (const float*)d_in[5];
  const float* bv = (const float*)d_in[6];
  float* out = (float*)d_out;

  const size_t MB = 1u << 20;
  if (ws_size < 116 * MB) return;

  char* ws = (char*)d_ws;
  half_t* xh   = (half_t*)(ws + 0);            // [B][N][C]    16 MB
  half_t* YTh  = (half_t*)(ws + 16 * MB);      // [B][N][C]    16 MB
  half_t* v    = (half_t*)(ws + 32 * MB);      // [B][C][N]    16 MB
  float*  S    = (float*)(ws + 48 * MB);       // [4][N][N]    64 MB (chunked)
  float*  Gp   = (float*)(ws + 48 * MB);       // [8][C][C]     8 MB (overlay; dead before S)
  half_t* Gh   = (half_t*)(ws + 112 * MB);     // [C][C]      0.5 MB
  half_t* Gl   = (half_t*)(ws + 112 * MB + 512 * 1024);
  half_t* wvh  = (half_t*)(ws + 113 * MB);     // [C][C]      0.5 MB
  float*  u    = (float*)(ws + 113 * MB + 512 * 1024);   // [C]      2 KB
  float*  ub   = (float*)(ws + 113 * MB + 768 * 1024);   // [B][N]  64 KB

  convert_w<<<1024, 256, 0, stream>>>(wv, wvh);
  compute_G_part<<<dim3(8, 8, 8), 256, 0, stream>>>(wq, wk, Gp);
  reduce_G<<<1024, 256, 0, stream>>>(Gp, Gh, Gl);
  compute_u<<<2, 256, 0, stream>>>(wk, bq, u);
  transpose_x<<<dim3(64, 16, 8), dim3(32, 8), 0, stream>>>(x, xh);
  compute_ubias<<<BB * NB / 4, 256, 0, stream>>>(xh, u, ub);

  // YT[b][j][c] = sum_d xh[b][j][d] * G[c][d]   (G-split 2-pass, single fp16 out)
  gemm_nt<0, 1, 1><<<dim3(4, 16, 8), 256, 0, stream>>>(
      xh, CB, (long)NB * CB, Gh, Gl, CB, 0,
      YTh, CB, (long)NB * CB, nullptr, 0, nullptr, 0, 0, CB);

  // v[b][c][n] = sum_cin wv[c][cin]*x[b][cin][n] + bv[c]   (plain fp16)
  gemm_nt<2, 1, 0><<<dim3(16, 4, 8), 256, 0, stream>>>(
      wvh, CB, 0, xh, nullptr, CB, (long)NB * CB,
      v, NB, (long)CB * NB, bv, 0, nullptr, 0, 0, CB);

  for (int c = 0; c < 2; c++) {
    size_t xoff = (size_t)c * 4 * NB * CB;
    // S[z][i][j] = sum_c xh[i][c]*YTh[j][c] + ub[z][j]   (plain fp16 single pass, f32 out)
    gemm_nt<1, 0, 0><<<dim3(16, 16, 4), 256, 0, stream>>>(
        xh + xoff, CB, (long)NB * CB,
        YTh + xoff, nullptr, CB, (long)NB * CB,
        S, NB, (long)NB * NB, ub + (size_t)c * 4 * NB, NB, nullptr, 0, 0, CB);

    softmax_rows<<<4 * NB, 256, 0, stream>>>(S);

    size_t ooff = (size_t)c * 4 * CB * NB;
    // out[z][ch][i] = sum_j v[z][ch][j]*P[z][i][j] + x[z][ch][i]   (P fp16 overlay, ld=4096)
    gemm_nt<0, 2, 0><<<dim3(16, 4, 4), 256, 0, stream>>>(
        v + ooff, NB, (long)CB * NB,
        (const half_t*)S, nullptr, 2 * NB, (long)NB * 2 * NB,
        out + ooff, NB, (long)CB * NB, nullptr, 0,
        x + ooff, NB, (long)CB * NB, NB);
  }
}

// Round 9
// 227.151 us; speedup vs baseline: 1.8940x; 1.1413x over previous
//
#include <hip/hip_runtime.h>
#include <hip/hip_bf16.h>

typedef _Float16 half_t;
typedef _Float16 f16x8 __attribute__((ext_vector_type(8)));
typedef float f32x4 __attribute__((ext_vector_type(4)));

#define AS1 __attribute__((address_space(1)))
#define AS3 __attribute__((address_space(3)))

constexpr int CB = 512;    // channels
constexpr int NB = 2048;   // sequence length
constexpr int BB = 8;      // batch

__device__ inline f32x4 mfma16(f16x8 a, f16x8 b, f32x4 c) {
  return __builtin_amdgcn_mfma_f32_16x16x32_f16(a, b, c, 0, 0, 0);
}

// ---------------- wv -> fp16
__global__ void convert_w(const float* __restrict__ wv, half_t* __restrict__ wvh) {
  int i = blockIdx.x * 256 + threadIdx.x;
  if (i < CB * CB) wvh[i] = (half_t)wv[i];
}

// ---------------- G partials: Gp[z][c][d] = sum_{o in chunk z} wq[o][c]*wk[o][d]
__global__ __launch_bounds__(256) void compute_G_part(const float* __restrict__ wq,
                                                      const float* __restrict__ wk,
                                                      float* __restrict__ Gp) {
  __shared__ float aq[64][68];
  __shared__ float ak[64][68];
  const int c0 = blockIdx.y * 64, d0 = blockIdx.x * 64, o0 = blockIdx.z * 64;
  const int t = threadIdx.x;
  {
    const int r = t >> 2, cbase = (t & 3) * 16;
    const float* q = wq + (size_t)(o0 + r) * CB + c0 + cbase;
    const float* k = wk + (size_t)(o0 + r) * CB + d0 + cbase;
#pragma unroll
    for (int q4 = 0; q4 < 4; q4++) {
      *(float4*)&aq[r][cbase + q4 * 4] = *(const float4*)(q + q4 * 4);
      *(float4*)&ak[r][cbase + q4 * 4] = *(const float4*)(k + q4 * 4);
    }
  }
  __syncthreads();
  const int tc = t & 15, td = t >> 4;
  float acc[4][4] = {};
#pragma unroll 8
  for (int o = 0; o < 64; o++) {
    float4 a4 = *(const float4*)&aq[o][tc * 4];
    float4 b4 = *(const float4*)&ak[o][td * 4];
    float av[4] = {a4.x, a4.y, a4.z, a4.w};
    float bv[4] = {b4.x, b4.y, b4.z, b4.w};
#pragma unroll
    for (int i = 0; i < 4; i++)
#pragma unroll
      for (int j = 0; j < 4; j++)
        acc[i][j] += av[i] * bv[j];
  }
  float* gz = Gp + (size_t)blockIdx.z * CB * CB;
#pragma unroll
  for (int i = 0; i < 4; i++) {
    int c = c0 + tc * 4 + i;
#pragma unroll
    for (int j = 0; j < 4; j++)
      gz[(size_t)c * CB + d0 + td * 4 + j] = acc[i][j];
  }
}

// ---------------- reduce 8 partials -> G hi/lo fp16
__global__ void reduce_G(const float* __restrict__ Gp,
                         half_t* __restrict__ Gh, half_t* __restrict__ Gl) {
  int i = blockIdx.x * 256 + threadIdx.x;
  if (i >= CB * CB) return;
  float s = 0.0f;
#pragma unroll
  for (int z = 0; z < 8; z++) s += Gp[(size_t)z * CB * CB + i];
  half_t h = (half_t)s;
  Gh[i] = h;
  Gl[i] = (half_t)(s - (float)h);
}

// ---------------- u[d] = sum_o bq[o]*wk[o][d]
__global__ void compute_u(const float* __restrict__ wk, const float* __restrict__ bq,
                          float* __restrict__ u) {
  int d = blockIdx.x * 256 + threadIdx.x;
  if (d >= CB) return;
  float s = 0.0f;
  for (int o = 0; o < CB; o++) s += bq[o] * wk[(size_t)o * CB + d];
  u[d] = s;
}

// ---------------- ubias[row] = sum_c u[c] * xh[row][c], row in [0, B*N)
__global__ __launch_bounds__(256) void compute_ubias(const half_t* __restrict__ xh,
                                                     const float* __restrict__ u,
                                                     float* __restrict__ ub) {
  __shared__ float us[CB];
  for (int i = threadIdx.x; i < CB; i += 256) us[i] = u[i];
  __syncthreads();
  int row = blockIdx.x * 4 + (threadIdx.x >> 6);
  int lane = threadIdx.x & 63;
  f16x8 vh = *(const f16x8*)(xh + (size_t)row * CB + lane * 8);
  float s = 0.0f;
#pragma unroll
  for (int i = 0; i < 8; i++) s += us[lane * 8 + i] * (float)vh[i];
#pragma unroll
  for (int off = 32; off; off >>= 1) s += __shfl_xor(s, off);
  if (lane == 0) ub[row] = s;
}

// ---------------- x [B][C][N] fp32 -> xh [B][N][C] fp16 (tiled transpose)
__global__ void transpose_x(const float* __restrict__ x, half_t* __restrict__ oh) {
  __shared__ float tile[32][33];
  int b = blockIdx.z, c0 = blockIdx.y * 32, n0 = blockIdx.x * 32;
  int tx = threadIdx.x, ty = threadIdx.y;          // block (32, 8)
  const float* xb = x + (size_t)b * CB * NB;
#pragma unroll
  for (int r = 0; r < 4; r++)
    tile[ty + 8 * r][tx] = xb[(size_t)(c0 + ty + 8 * r) * NB + n0 + tx];
  __syncthreads();
  size_t base = (size_t)b * NB * CB;
#pragma unroll
  for (int r = 0; r < 4; r++)
    oh[base + (size_t)(n0 + ty + 8 * r) * CB + c0 + tx] = (half_t)tile[tx][ty + 8 * r];
}

// ---------------- GEMM-NT (proven 128^2 2-barrier, fp16):  D[M][N] = A[M][K] * B[N][K]^T
// BSPLIT: 1 -> B has hi/lo planes, 2 MFMA passes (A*Bh + A*Bl); A always 1 plane.
// BIAS: 0 none, 1 batched col-bias f32, 2 row-bias f32
// EPI: 0 f32 store; 1 fp16 store; 2 f32 store + residual R(f32)
template <int BIAS, int EPI, int BSPLIT>
__global__ __launch_bounds__(256) void gemm_nt(
    const half_t* __restrict__ A, int lda, long sA,
    const half_t* __restrict__ Bh, const half_t* __restrict__ Bl, int ldb, long sB,
    void* __restrict__ D, int ldd, long sD,
    const float* __restrict__ bias, long sBias,
    const float* __restrict__ R, int ldr, long sR,
    int K) {
  constexpr int PL = 2 + BSPLIT;                 // planes: A, Bh, (Bl)
  constexpr int TSZ = 128 * 32;                  // elems per plane tile (8KB)
  __shared__ alignas(16) half_t sm[2 * PL * TSZ];

  const int t = threadIdx.x;
  const int z = blockIdx.z;
  const half_t* Ab  = A  + (size_t)z * sA + (size_t)(blockIdx.y * 128) * lda;
  const half_t* Bbh = Bh + (size_t)z * sB + (size_t)(blockIdx.x * 128) * ldb;
  const half_t* Bbl = BSPLIT ? Bl + (size_t)z * sB + (size_t)(blockIdx.x * 128) * ldb : nullptr;
  const int wid = t >> 6, l15 = t & 15, hi = (t >> 4) & 3;
  const int wr = wid >> 1, wc = wid & 1;
  const int lineA = t >> 2, eoff = (t & 3) * 8;

  f32x4 acc[4][4] = {};

  auto stage = [&](int buf, int kt) {
    half_t* base = sm + buf * (PL * TSZ);
#pragma unroll
    for (int p = 0; p < 2; p++) {
      size_t goA = (size_t)(p * 64 + lineA) * lda + kt * 32 + eoff;
      size_t goB = (size_t)(p * 64 + lineA) * ldb + kt * 32 + eoff;
      int lo = p * 2048 + t * 8;
      __builtin_amdgcn_global_load_lds((const AS1 void*)(Ab + goA),  (AS3 void*)(base + lo), 16, 0, 0);
      __builtin_amdgcn_global_load_lds((const AS1 void*)(Bbh + goB), (AS3 void*)(base + TSZ + lo), 16, 0, 0);
      if (BSPLIT)
        __builtin_amdgcn_global_load_lds((const AS1 void*)(Bbl + goB), (AS3 void*)(base + 2 * TSZ + lo), 16, 0, 0);
    }
  };

  const int nt = K >> 5;
  stage(0, 0);
  __syncthreads();
  int cur = 0;
  for (int kt = 0; kt < nt; kt++) {
    if (kt + 1 < nt) stage(cur ^ 1, kt + 1);
    const half_t* bb = sm + cur * (PL * TSZ);
    f16x8 af[4], bfh[4], bfl[4];
#pragma unroll
    for (int f = 0; f < 4; f++) {
      int ao = (wr * 64 + f * 16 + l15) * 32 + hi * 8;
      int bo = (wc * 64 + f * 16 + l15) * 32 + hi * 8;
      af[f]  = *(const f16x8*)(bb + ao);
      bfh[f] = *(const f16x8*)(bb + TSZ + bo);
      if (BSPLIT) bfl[f] = *(const f16x8*)(bb + 2 * TSZ + bo);
    }
#pragma unroll
    for (int pass = 0; pass < 1 + BSPLIT; pass++) {
#pragma unroll
      for (int fm = 0; fm < 4; fm++)
#pragma unroll
        for (int fn = 0; fn < 4; fn++)
          acc[fm][fn] = mfma16(af[fm], (pass == 1) ? bfl[fn] : bfh[fn], acc[fm][fn]);
    }
    __syncthreads();
    cur ^= 1;
  }

  const int row0 = blockIdx.y * 128 + wr * 64;
  const int col0 = blockIdx.x * 128 + wc * 64;
#pragma unroll
  for (int fm = 0; fm < 4; fm++) {
    int rowb = row0 + fm * 16 + hi * 4;
#pragma unroll
    for (int fn = 0; fn < 4; fn++) {
      int col = col0 + fn * 16 + l15;
      float bc = (BIAS == 1) ? bias[(size_t)z * sBias + col] : 0.0f;
#pragma unroll
      for (int r = 0; r < 4; r++) {
        float val = acc[fm][fn][r] + bc;
        if (BIAS == 2) val += bias[(size_t)z * sBias + rowb + r];
        size_t di = (size_t)(rowb + r) * ldd + col;
        if (EPI == 0) {
          ((float*)D)[(size_t)z * sD + di] = val;
        } else if (EPI == 1) {
          ((half_t*)D)[(size_t)z * sD + di] = (half_t)val;
        } else {  // EPI == 2
          val += R[(size_t)z * sR + (size_t)(rowb + r) * ldr + col];
          ((float*)D)[(size_t)z * sD + di] = val;
        }
      }
    }
  }
}

// ---------------- row softmax over S fp32 [rows][2048]; writes P fp16 in-place at row base
struct alignas(16) H8 { half_t h[8]; };

__global__ __launch_bounds__(256) void softmax_rows(float* __restrict__ S) {
  float* row = S + (size_t)blockIdx.x * NB;
  int t = threadIdx.x;
  float4 v0 = ((const float4*)row)[t * 2];
  float4 v1 = ((const float4*)row)[t * 2 + 1];
  float vals[8] = {v0.x, v0.y, v0.z, v0.w, v1.x, v1.y, v1.z, v1.w};
  float m = vals[0];
#pragma unroll
  for (int i = 1; i < 8; i++) m = fmaxf(m, vals[i]);
#pragma unroll
  for (int off = 32; off; off >>= 1) m = fmaxf(m, __shfl_xor(m, off));
  __shared__ float redm[4], reds[4];
  if ((t & 63) == 0) redm[t >> 6] = m;
  __syncthreads();
  m = fmaxf(fmaxf(redm[0], redm[1]), fmaxf(redm[2], redm[3]));
  float e[8], s = 0.0f;
#pragma unroll
  for (int i = 0; i < 8; i++) { e[i] = __expf(vals[i] - m); s += e[i]; }
#pragma unroll
  for (int off = 32; off; off >>= 1) s += __shfl_xor(s, off);
  if ((t & 63) == 0) reds[t >> 6] = s;
  __syncthreads();
  s = reds[0] + reds[1] + reds[2] + reds[3];
  float inv = 1.0f / s;
  H8 ob;
#pragma unroll
  for (int i = 0; i < 8; i++) ob.h[i] = (half_t)(e[i] * inv);
  *reinterpret_cast<H8*>(reinterpret_cast<char*>(row) + t * 16) = ob;
}

// ---------------- launcher
extern "C" void kernel_launch(void* const* d_in, const int* in_sizes, int n_in,
                              void* d_out, int out_size, void* d_ws, size_t ws_size,
                              hipStream_t stream) {
  const float* x  = (const float*)d_in[0];
  const float* wq = (const float*)d_in[1];
  const float* bq = (const float*)d_in[2];
  const float* wk = (const float*)d_in[3];
  const float* wv = (const float*)d_in[5];
  const float* bv = (const float*)d_in[6];
  float* out = (float*)d_out;

  const size_t MB = 1u << 20;
  if (ws_size < 180 * MB) return;

  char* ws = (char*)d_ws;
  half_t* xh   = (half_t*)(ws + 0);            // [B][N][C]    16 MB
  half_t* YTh  = (half_t*)(ws + 16 * MB);      // [B][N][C]    16 MB
  half_t* v    = (half_t*)(ws + 32 * MB);      // [B][C][N]    16 MB
  float*  S    = (float*)(ws + 48 * MB);       // [8][N][N]   128 MB (full batch)
  float*  Gp   = (float*)(ws + 48 * MB);       // [8][C][C]     8 MB (overlay; dead before S)
  half_t* Gh   = (half_t*)(ws + 176 * MB);     // [C][C]      0.5 MB
  half_t* Gl   = (half_t*)(ws + 176 * MB + 512 * 1024);
  half_t* wvh  = (half_t*)(ws + 177 * MB);     // [C][C]      0.5 MB
  float*  u    = (float*)(ws + 177 * MB + 512 * 1024);   // [C]      2 KB
  float*  ub   = (float*)(ws + 177 * MB + 768 * 1024);   // [B][N]  64 KB

  convert_w<<<1024, 256, 0, stream>>>(wv, wvh);
  compute_G_part<<<dim3(8, 8, 8), 256, 0, stream>>>(wq, wk, Gp);
  reduce_G<<<1024, 256, 0, stream>>>(Gp, Gh, Gl);
  compute_u<<<2, 256, 0, stream>>>(wk, bq, u);
  transpose_x<<<dim3(64, 16, 8), dim3(32, 8), 0, stream>>>(x, xh);
  compute_ubias<<<BB * NB / 4, 256, 0, stream>>>(xh, u, ub);

  // YT[b][j][c] = sum_d xh[b][j][d] * G[c][d]   (G-split 2-pass, single fp16 out)
  gemm_nt<0, 1, 1><<<dim3(4, 16, 8), 256, 0, stream>>>(
      xh, CB, (long)NB * CB, Gh, Gl, CB, 0,
      YTh, CB, (long)NB * CB, nullptr, 0, nullptr, 0, 0, CB);

  // v[b][c][n] = sum_cin wv[c][cin]*x[b][cin][n] + bv[c]   (plain fp16)
  gemm_nt<2, 1, 0><<<dim3(16, 4, 8), 256, 0, stream>>>(
      wvh, CB, 0, xh, nullptr, CB, (long)NB * CB,
      v, NB, (long)CB * NB, bv, 0, nullptr, 0, 0, CB);

  // S[z][i][j] = sum_c xh[i][c]*YTh[j][c] + ub[z][j]   (full batch, single dispatch)
  gemm_nt<1, 0, 0><<<dim3(16, 16, 8), 256, 0, stream>>>(
      xh, CB, (long)NB * CB,
      YTh, nullptr, CB, (long)NB * CB,
      S, NB, (long)NB * NB, ub, NB, nullptr, 0, 0, CB);

  softmax_rows<<<BB * NB, 256, 0, stream>>>(S);

  // out[z][ch][i] = sum_j v[z][ch][j]*P[z][i][j] + x[z][ch][i]   (P fp16 overlay, ld=4096)
  gemm_nt<0, 2, 0><<<dim3(16, 4, 8), 256, 0, stream>>>(
      v, NB, (long)CB * NB,
      (const half_t*)S, nullptr, 2 * NB, (long)NB * 2 * NB,
      out, NB, (long)CB * NB, nullptr, 0,
      x, NB, (long)CB * NB, NB);
}